// Round 5
// baseline (42.502 us; speedup 1.0000x reference)
//
#include <hip/hip_runtime.h>
#include <hip/hip_bf16.h>

#define NBINS 20
#define TPB 256

// Non-atomic LDS RMW histogram, s[bin][tid] private column per thread.
// LDS = 20*256*4 = 20480 B exactly -> 8 blocks/CU = 32 waves/CU (100%).
// bin = ceil((c-0.5)*40)-1 matches searchsorted(side='left')-1 (absmax 0.0,
// rounds 1-4). Invalid samples (c<=0.5 or c>1, ~50% of data) are exec-masked
// off. Prefetch depth 1 keeps 4 dwordx4 loads in flight under the RMW chain.
__global__ __launch_bounds__(TPB, 8) void ece_accum(
        const float4* __restrict__ confs,
        const float4* __restrict__ accs,
        int n8,                        // n/8
        float* __restrict__ partials,  // [NBINS][nb]
        int nb) {
    __shared__ float s[NBINS * TPB];
    const int t = threadIdx.x;
#pragma unroll
    for (int k = 0; k < NBINS; ++k) s[k * TPB + t] = 0.0f;
    __syncthreads();

    const int stride = gridDim.x * TPB;
    int i = blockIdx.x * TPB + t;

    float4 c0, c1, a0, a1;
    bool have = (i < n8);
    if (have) {
        c0 = confs[2 * i];
        c1 = confs[2 * i + 1];
        a0 = accs[2 * i];
        a1 = accs[2 * i + 1];
    }

    while (have) {
        const int inext = i + stride;
        const bool hnext = (inext < n8);
        float4 nc0, nc1, na0, na1;
        if (hnext) {  // issue next-iteration loads BEFORE the RMW chain
            nc0 = confs[2 * inext];
            nc1 = confs[2 * inext + 1];
            na0 = accs[2 * inext];
            na1 = accs[2 * inext + 1];
        }

#pragma unroll
        for (int j = 0; j < 8; ++j) {
            float c, a;
            switch (j) {
                case 0: c = c0.x; a = a0.x; break;
                case 1: c = c0.y; a = a0.y; break;
                case 2: c = c0.z; a = a0.z; break;
                case 3: c = c0.w; a = a0.w; break;
                case 4: c = c1.x; a = a1.x; break;
                case 5: c = c1.y; a = a1.y; break;
                case 6: c = c1.z; a = a1.z; break;
                default: c = c1.w; a = a1.w; break;
            }
            float ft = __builtin_ceilf((c - 0.5f) * 40.0f);
            unsigned int bin = (unsigned int)((int)ft - 1);
            if (bin < (unsigned int)NBINS)
                s[bin * TPB + t] += c - a;  // ds_read + v_add + ds_write
        }

        i = inext;
        have = hnext;
        c0 = nc0; c1 = nc1; a0 = na0; a1 = na1;
    }
    __syncthreads();

    // block reduce, reusing s[] (no extra LDS)
    float v[NBINS];
#pragma unroll
    for (int b = 0; b < NBINS; ++b) v[b] = s[b * TPB + t];
#pragma unroll
    for (int b = 0; b < NBINS; ++b) {
#pragma unroll
        for (int m = 32; m >= 1; m >>= 1) v[b] += __shfl_xor(v[b], m, 64);
    }
    __syncthreads();  // all reads of s done before overwrite
    const int wave = t >> 6, lane = t & 63;
    if (lane == 0) {
#pragma unroll
        for (int b = 0; b < NBINS; ++b) s[b * 4 + wave] = v[b];
    }
    __syncthreads();
    if (t < NBINS) {
        float sum = s[t * 4 + 0] + s[t * 4 + 1] + s[t * 4 + 2] + s[t * 4 + 3];
        partials[t * nb + blockIdx.x] = sum;
    }
}

// One block: reduce nb partials per bin, ece = sum_b |S_b| / N
__global__ __launch_bounds__(512) void ece_final(
        const float* __restrict__ partials,
        float* __restrict__ out,
        float inv_n, int nb) {
    float s[NBINS];
#pragma unroll
    for (int b = 0; b < NBINS; ++b) s[b] = 0.0f;

    const int tid = threadIdx.x;
    const int nb4 = nb >> 2;  // nb is a multiple of 4
#pragma unroll
    for (int b = 0; b < NBINS; ++b) {
        const float4* pb = (const float4*)(partials + b * nb);
        for (int k = tid; k < nb4; k += blockDim.x) {
            float4 v = pb[k];
            s[b] += (v.x + v.y) + (v.z + v.w);
        }
    }
#pragma unroll
    for (int b = 0; b < NBINS; ++b) {
#pragma unroll
        for (int m = 32; m >= 1; m >>= 1)
            s[b] += __shfl_xor(s[b], m, 64);
    }

    __shared__ float red[NBINS][8];
    const int wave = tid >> 6;
    const int lane = tid & 63;
    if (lane == 0) {
#pragma unroll
        for (int b = 0; b < NBINS; ++b) red[b][wave] = s[b];
    }
    __syncthreads();

    if (tid == 0) {
        float ece = 0.0f;
#pragma unroll
        for (int b = 0; b < NBINS; ++b) {
            float tt = 0.0f;
#pragma unroll
            for (int w = 0; w < 8; ++w) tt += red[b][w];
            ece += fabsf(tt);
        }
        out[0] = ece * inv_n;
    }
}

extern "C" void kernel_launch(void* const* d_in, const int* in_sizes, int n_in,
                              void* d_out, int out_size, void* d_ws, size_t ws_size,
                              hipStream_t stream) {
    const float* confs = (const float*)d_in[0];
    const float* accs = (const float*)d_in[1];
    const int n = in_sizes[0];   // 16,777,216
    const int n8 = n / 8;

    // 8 blocks/CU at 20 KB LDS -> 2048 blocks, exactly 4 iters/thread
    int nb = 2048;
    int ws_cap = (int)(ws_size / (NBINS * sizeof(float)));
    ws_cap &= ~3;
    if (nb > ws_cap) nb = ws_cap;
    if (nb < 4) nb = 4;

    float* partials = (float*)d_ws;

    ece_accum<<<nb, TPB, 0, stream>>>((const float4*)confs, (const float4*)accs,
                                      n8, partials, nb);
    ece_final<<<1, 512, 0, stream>>>(partials, (float*)d_out, 1.0f / (float)n, nb);
}